// Round 3
// baseline (162.746 us; speedup 1.0000x reference)
//
#include <hip/hip_runtime.h>
#include <hip/hip_bf16.h>

constexpr int kEmbed = 128;
constexpr int kBatch = 65536;
constexpr int kNeg   = 10;
constexpr float kEps = 1e-10f;

// One 32-lane group per sample b. Lane l owns float4 at column 4*l (16B/lane,
// 512B/row, fully coalesced). 12 gathered rows per sample, 12 dot products,
// 5-step shfl_xor butterfly (stays within the 32-lane half-wave), fast
// exp/log (scores ~1e-4, sigmoid ~0.5 -> no range issues).
__global__ __launch_bounds__(256, 4) void sgns_loss_kernel(
    const float* __restrict__ tw,
    const float* __restrict__ cw,
    const int*   __restrict__ t,
    const int*   __restrict__ c,
    const int*   __restrict__ n,
    float*       __restrict__ out)
{
    const int tid     = threadIdx.x;
    const int lane    = tid & 31;
    const int group   = (blockIdx.x * blockDim.x + tid) >> 5;
    const int ngroups = (gridDim.x * blockDim.x) >> 5;

    float acc = 0.0f;

    for (int b = group; b < kBatch; b += ngroups) {
        const int it = t[b];
        const int ic = c[b];
        int ni[kNeg];
        #pragma unroll
        for (int k = 0; k < kNeg; ++k) ni[k] = n[b * kNeg + k];

        const float4 vt = *reinterpret_cast<const float4*>(tw + (size_t)it * kEmbed + 4 * lane);
        const float4 vc = *reinterpret_cast<const float4*>(cw + (size_t)ic * kEmbed + 4 * lane);

        float s[kNeg + 1];
        s[0] = vt.x * vc.x + vt.y * vc.y + vt.z * vc.z + vt.w * vc.w;

        #pragma unroll
        for (int k = 0; k < kNeg; ++k) {
            const float4 vn = *reinterpret_cast<const float4*>(
                cw + (size_t)ni[k] * kEmbed + 4 * lane);
            s[k + 1] = vt.x * vn.x + vt.y * vn.y + vt.z * vn.z + vt.w * vn.w;
        }

        // Butterfly reduce each score across the 32-lane group.
        #pragma unroll
        for (int k = 0; k < kNeg + 1; ++k) {
            float v = s[k];
            v += __shfl_xor(v, 16);
            v += __shfl_xor(v, 8);
            v += __shfl_xor(v, 4);
            v += __shfl_xor(v, 2);
            v += __shfl_xor(v, 1);
            s[k] = v;
        }

        // pos: log(sigmoid(s0)+eps); negs: log(sigmoid(-sk)+eps) = log(1/(1+e^{sk})+eps)
        float lb = __logf(1.0f / (1.0f + __expf(-s[0])) + kEps);
        #pragma unroll
        for (int k = 1; k < kNeg + 1; ++k)
            lb += __logf(1.0f / (1.0f + __expf(s[k])) + kEps);

        // All 32 lanes hold the same lb; only lane 0 accumulates.
        if (lane == 0) acc += lb;
    }

    // Block reduction: full 64-lane butterfly, then LDS across the 4 waves.
    #pragma unroll
    for (int m = 32; m >= 1; m >>= 1) acc += __shfl_xor(acc, m);

    __shared__ float wave_sum[4];
    if ((tid & 63) == 0) wave_sum[tid >> 6] = acc;
    __syncthreads();
    if (tid == 0) {
        const float s4 = wave_sum[0] + wave_sum[1] + wave_sum[2] + wave_sum[3];
        atomicAdd(out, s4 * (-1.0f / (float)kBatch));
    }
}

extern "C" void kernel_launch(void* const* d_in, const int* in_sizes, int n_in,
                              void* d_out, int out_size, void* d_ws, size_t ws_size,
                              hipStream_t stream) {
    const float* tw = (const float*)d_in[0];
    const float* cw = (const float*)d_in[1];
    const int*   t  = (const int*)d_in[2];
    const int*   c  = (const int*)d_in[3];
    const int*   n  = (const int*)d_in[4];
    float* out = (float*)d_out;

    // d_out is re-poisoned to 0xAA before every launch; zero it ourselves.
    hipMemsetAsync(out, 0, sizeof(float), stream);

    // 2048 blocks x 256 threads = 16384 groups -> 4 samples per group.
    sgns_loss_kernel<<<2048, 256, 0, stream>>>(tw, cw, t, c, n, out);
}